// Round 1
// baseline (1687.710 us; speedup 1.0000x reference)
//
#include <hip/hip_runtime.h>
#include <hip/hip_bf16.h>
#include <cstdint>

#define BB   4
#define TT   2048
#define HH   1024
#define NHH  16
#define DHH  64
#define MM   (BB*TT)      // 8192
#define N3   (3*HH)       // 3072

__device__ __forceinline__ float bf2f(unsigned short u) {
    return __uint_as_float(((uint32_t)u) << 16);
}
__device__ __forceinline__ unsigned short f2bf(float f) {
    uint32_t u = __float_as_uint(f);
    uint32_t r = (u + 0x7fffu + ((u >> 16) & 1u)) >> 16;  // RNE
    return (unsigned short)r;
}

// ---------------------------------------------------------------------------
// Kernel A: QKV projections. C[M][3H] (bf16) = x[M][1024] @ W^T, W in {Wq,Wk,Wv}
// picked by column block (1024-col slabs). 128x128 tile, BK=16, 256 thr, 8x8/thr
// split as 4+4 (cols {tx*4..+4} and {64+tx*4..+4}) to keep LDS reads 2-way max.
// ---------------------------------------------------------------------------
__global__ __launch_bounds__(256) void proj_gemm(
    const float* __restrict__ x, const float* __restrict__ Wq,
    const float* __restrict__ Wk, const float* __restrict__ Wv,
    unsigned short* __restrict__ C)
{
    __shared__ float As[16][132];  // [k][m], pad to 132
    __shared__ float Bs[16][132];  // [k][n]
    const int m0 = blockIdx.x * 128;
    const int n0 = blockIdx.y * 128;
    const float* W = (n0 < HH) ? Wq : (n0 < 2*HH ? Wk : Wv);
    const int nw0 = n0 & (HH - 1);
    const int tid = threadIdx.x;
    const int tx = tid & 15, ty = tid >> 4;

    float acc[8][8];
    #pragma unroll
    for (int i = 0; i < 8; ++i)
        #pragma unroll
        for (int j = 0; j < 8; ++j) acc[i][j] = 0.f;

    const int lr = tid >> 2;        // 0..63 (row within tile, +64 on 2nd iter)
    const int lk = (tid & 3) * 4;   // 0,4,8,12

    for (int k0 = 0; k0 < HH; k0 += 16) {
        __syncthreads();
        #pragma unroll
        for (int it = 0; it < 2; ++it) {
            const int row = lr + it * 64;
            float4 av = *(const float4*)&x[(size_t)(m0 + row) * HH + k0 + lk];
            As[lk+0][row] = av.x; As[lk+1][row] = av.y;
            As[lk+2][row] = av.z; As[lk+3][row] = av.w;
            float4 bv = *(const float4*)&W[(size_t)(nw0 + row) * HH + k0 + lk];
            Bs[lk+0][row] = bv.x; Bs[lk+1][row] = bv.y;
            Bs[lk+2][row] = bv.z; Bs[lk+3][row] = bv.w;
        }
        __syncthreads();
        #pragma unroll
        for (int k = 0; k < 16; ++k) {
            float a0[8], b0[8];
            *(float4*)&a0[0] = *(const float4*)&As[k][ty*4];
            *(float4*)&a0[4] = *(const float4*)&As[k][64 + ty*4];
            *(float4*)&b0[0] = *(const float4*)&Bs[k][tx*4];
            *(float4*)&b0[4] = *(const float4*)&Bs[k][64 + tx*4];
            #pragma unroll
            for (int i = 0; i < 8; ++i)
                #pragma unroll
                for (int j = 0; j < 8; ++j)
                    acc[i][j] += a0[i] * b0[j];
        }
    }
    // epilogue: bf16 store
    #pragma unroll
    for (int i = 0; i < 8; ++i) {
        const int r = m0 + ((i < 4) ? (ty*4 + i) : (64 + ty*4 + (i - 4)));
        #pragma unroll
        for (int j = 0; j < 8; ++j) {
            const int c = n0 + ((j < 4) ? (tx*4 + j) : (64 + tx*4 + (j - 4)));
            C[(size_t)r * N3 + c] = f2bf(acc[i][j]);
        }
    }
}

// ---------------------------------------------------------------------------
// Kernel B: per (b,h,t-block of 64): phase A computes l_t = sum_s exp(S[t,s]/8)
// (no max-subtraction; |S| is small), phase B recomputes S and accumulates
// a[b,h,s] += (1/T) * sum_t exp(S)/l_t via one atomicAdd per s per block.
// ---------------------------------------------------------------------------
__global__ __launch_bounds__(256) void attn_colsum(
    const unsigned short* __restrict__ qkv, float* __restrict__ a)
{
    const int tb = blockIdx.x;   // 0..31
    const int h  = blockIdx.y;   // 0..15
    const int b  = blockIdx.z;   // 0..3
    const int tid = threadIdx.x;
    const int tx = tid & 15, ty = tid >> 4;
    __shared__ float Qs[64][68];   // [k][t]
    __shared__ float Ks[64][68];   // [k][s]
    __shared__ float red[64][17];
    __shared__ float linv[64];
    const int t0 = tb * 64;

    // stage Q tile (64 t x 64 k), bf16 -> f32, transposed to [k][t]
    #pragma unroll
    for (int it = 0; it < 2; ++it) {
        const int uu = tid + it * 256;
        const int t = uu >> 3, part = uu & 7;
        uint4 raw = *(const uint4*)&qkv[(size_t)(b*TT + t0 + t) * N3 + h*DHH + part*8];
        unsigned short us[8];
        *(uint4*)us = raw;
        #pragma unroll
        for (int j = 0; j < 8; ++j) Qs[part*8 + j][t] = bf2f(us[j]);
    }

    // ---- phase A: row sums l_t ----
    float lpart[4] = {0.f, 0.f, 0.f, 0.f};
    for (int s0 = 0; s0 < TT; s0 += 64) {
        __syncthreads();
        #pragma unroll
        for (int it = 0; it < 2; ++it) {
            const int uu = tid + it * 256;
            const int s = uu >> 3, part = uu & 7;
            uint4 raw = *(const uint4*)&qkv[(size_t)(b*TT + s0 + s) * N3 + HH + h*DHH + part*8];
            unsigned short us[8];
            *(uint4*)us = raw;
            #pragma unroll
            for (int j = 0; j < 8; ++j) Ks[part*8 + j][s] = bf2f(us[j]);
        }
        __syncthreads();
        float acc[4][4];
        #pragma unroll
        for (int i = 0; i < 4; ++i)
            #pragma unroll
            for (int j = 0; j < 4; ++j) acc[i][j] = 0.f;
        #pragma unroll 8
        for (int k = 0; k < 64; ++k) {
            float qv[4], kv[4];
            *(float4*)qv = *(const float4*)&Qs[k][ty*4];
            *(float4*)kv = *(const float4*)&Ks[k][tx*4];
            #pragma unroll
            for (int i = 0; i < 4; ++i)
                #pragma unroll
                for (int j = 0; j < 4; ++j) acc[i][j] += qv[i] * kv[j];
        }
        #pragma unroll
        for (int i = 0; i < 4; ++i)
            #pragma unroll
            for (int j = 0; j < 4; ++j) lpart[i] += __expf(acc[i][j] * 0.125f);
    }
    __syncthreads();
    #pragma unroll
    for (int i = 0; i < 4; ++i) red[ty*4 + i][tx] = lpart[i];
    __syncthreads();
    if (tid < 64) {
        float s = 0.f;
        #pragma unroll
        for (int x2 = 0; x2 < 16; ++x2) s += red[tid][x2];
        linv[tid] = 1.0f / s;
    }

    // ---- phase B: column sums into a ----
    for (int s0 = 0; s0 < TT; s0 += 64) {
        __syncthreads();
        #pragma unroll
        for (int it = 0; it < 2; ++it) {
            const int uu = tid + it * 256;
            const int s = uu >> 3, part = uu & 7;
            uint4 raw = *(const uint4*)&qkv[(size_t)(b*TT + s0 + s) * N3 + HH + h*DHH + part*8];
            unsigned short us[8];
            *(uint4*)us = raw;
            #pragma unroll
            for (int j = 0; j < 8; ++j) Ks[part*8 + j][s] = bf2f(us[j]);
        }
        __syncthreads();
        float acc[4][4];
        #pragma unroll
        for (int i = 0; i < 4; ++i)
            #pragma unroll
            for (int j = 0; j < 4; ++j) acc[i][j] = 0.f;
        #pragma unroll 8
        for (int k = 0; k < 64; ++k) {
            float qv[4], kv[4];
            *(float4*)qv = *(const float4*)&Qs[k][ty*4];
            *(float4*)kv = *(const float4*)&Ks[k][tx*4];
            #pragma unroll
            for (int i = 0; i < 4; ++i)
                #pragma unroll
                for (int j = 0; j < 4; ++j) acc[i][j] += qv[i] * kv[j];
        }
        float li[4];
        #pragma unroll
        for (int i = 0; i < 4; ++i) li[i] = linv[ty*4 + i];
        float cpart[4] = {0.f, 0.f, 0.f, 0.f};
        #pragma unroll
        for (int i = 0; i < 4; ++i)
            #pragma unroll
            for (int j = 0; j < 4; ++j)
                cpart[j] += __expf(acc[i][j] * 0.125f) * li[i];
        __syncthreads();
        #pragma unroll
        for (int j = 0; j < 4; ++j) red[tx*4 + j][ty] = cpart[j];
        __syncthreads();
        if (tid < 64) {
            float s = 0.f;
            #pragma unroll
            for (int y2 = 0; y2 < 16; ++y2) s += red[tid][y2];
            atomicAdd(&a[(size_t)(b*NHH + h) * TT + s0 + tid], s * (1.0f / TT));
        }
    }
}

// ---------------------------------------------------------------------------
// Kernel C: cm[b, h*64+d] = sum_s a[b,h,s] * V[b,s,h*64+d]
// ---------------------------------------------------------------------------
__global__ __launch_bounds__(256) void ctx_mean(
    const unsigned short* __restrict__ qkv, const float* __restrict__ a,
    float* __restrict__ cm)
{
    const int h = blockIdx.x, b = blockIdx.y;
    const int tid = threadIdx.x;
    const int d = tid & 63, sg = tid >> 6;
    __shared__ float red[4][64];
    float part = 0.f;
    for (int s = sg; s < TT; s += 4) {
        const float av = a[(size_t)(b*NHH + h) * TT + s];
        const float vv = bf2f(qkv[(size_t)(b*TT + s) * N3 + 2*HH + h*DHH + d]);
        part += av * vv;
    }
    red[sg][d] = part;
    __syncthreads();
    if (tid < 64) {
        cm[b*HH + h*DHH + tid] =
            red[0][tid] + red[1][tid] + red[2][tid] + red[3][tid];
    }
}

// ---------------------------------------------------------------------------
// Kernel D: out[b][j] = bo[j] + sum_k cm[b][k] * Wo[j][k]
// grid (16, B); block 256 = 64 j x 4 k-groups; shuffle-reduce groups of 4.
// ---------------------------------------------------------------------------
__global__ __launch_bounds__(256) void out_proj(
    const float* __restrict__ cm, const float* __restrict__ Wo,
    const float* __restrict__ bo, float* __restrict__ out)
{
    const int b = blockIdx.y;
    const int jb = blockIdx.x;
    const int tid = threadIdx.x;
    const int j = jb * 64 + (tid >> 2);
    const int kg = tid & 3;
    __shared__ float cs[HH];
    for (int k = tid; k < HH; k += 256) cs[k] = cm[b*HH + k];
    __syncthreads();
    float acc = 0.f;
    const float* wrow = &Wo[(size_t)j * HH];
    #pragma unroll 8
    for (int i = 0; i < 64; ++i) {
        const int k = kg * 256 + i * 4;
        float4 w4 = *(const float4*)&wrow[k];
        acc += w4.x * cs[k] + w4.y * cs[k+1] + w4.z * cs[k+2] + w4.w * cs[k+3];
    }
    acc += __shfl_down(acc, 2, 4);
    acc += __shfl_down(acc, 1, 4);
    if (kg == 0) out[b*HH + j] = acc + bo[j];
}

// ---------------------------------------------------------------------------
extern "C" void kernel_launch(void* const* d_in, const int* in_sizes, int n_in,
                              void* d_out, int out_size, void* d_ws, size_t ws_size,
                              hipStream_t stream) {
    const float* x  = (const float*)d_in[0];
    const float* Wq = (const float*)d_in[1];
    const float* Wk = (const float*)d_in[2];
    const float* Wv = (const float*)d_in[3];
    const float* Wo = (const float*)d_in[4];
    const float* bo = (const float*)d_in[5];
    float* out = (float*)d_out;

    unsigned short* qkv = (unsigned short*)d_ws;           // [M][3H] bf16, 50.3 MB
    const size_t qkv_bytes = (size_t)MM * N3 * sizeof(unsigned short);
    float* a  = (float*)((char*)d_ws + qkv_bytes);          // [B][NH][T], 0.5 MB
    float* cm = a + (size_t)BB * NHH * TT;                  // [B][H], 16 KB

    hipMemsetAsync(a, 0, (size_t)BB * NHH * TT * sizeof(float), stream);
    proj_gemm  <<<dim3(64, 24),       256, 0, stream>>>(x, Wq, Wk, Wv, qkv);
    attn_colsum<<<dim3(32, NHH, BB),  256, 0, stream>>>(qkv, a);
    ctx_mean   <<<dim3(NHH, BB),      256, 0, stream>>>(qkv, a, cm);
    out_proj   <<<dim3(16, BB),       256, 0, stream>>>(cm, Wo, bo, out);
}

// Round 2
// 419.039 us; speedup vs baseline: 4.0276x; 4.0276x over previous
//
#include <hip/hip_runtime.h>
#include <hip/hip_bf16.h>
#include <cstdint>

#define BB   4
#define TT   2048
#define HH   1024
#define NHH  16
#define DHH  64
#define MM   (BB*TT)      // 8192
#define N3   (3*HH)       // 3072

typedef __attribute__((ext_vector_type(8))) short short8;   // 8 bf16 = 4 VGPR
typedef __attribute__((ext_vector_type(4))) float f32x4;

__device__ __forceinline__ float bf2f(unsigned short u) {
    return __uint_as_float(((uint32_t)u) << 16);
}
__device__ __forceinline__ unsigned short f2bf(float f) {
    uint32_t u = __float_as_uint(f);
    return (unsigned short)((u + 0x7fffu + ((u >> 16) & 1u)) >> 16);  // RNE
}
__device__ __forceinline__ void gload_lds16(const unsigned short* g, unsigned short* l) {
    __builtin_amdgcn_global_load_lds(
        (const __attribute__((address_space(1))) uint32_t*)g,
        (__attribute__((address_space(3))) uint32_t*)l, 16, 0, 0);
}

// ---------------------------------------------------------------------------
// f32 -> bf16 bulk convert (vectorized, grid-stride)
// ---------------------------------------------------------------------------
__global__ __launch_bounds__(256) void cvt_bf16(
    const float* __restrict__ src, unsigned short* __restrict__ dst, int n4)
{
    int i = blockIdx.x * 256 + threadIdx.x;
    const int stride = gridDim.x * 256;
    for (; i < n4; i += stride) {
        float4 v = ((const float4*)src)[i];
        ushort4 o;
        o.x = f2bf(v.x); o.y = f2bf(v.y); o.z = f2bf(v.z); o.w = f2bf(v.w);
        ((ushort4*)dst)[i] = o;
    }
}

// ---------------------------------------------------------------------------
// QKV projection: C[M][3H] bf16 = xb[M][1024] @ Wb[sel]^T   (MFMA 16x16x32)
// 128x128 tile, BK=32, 256 thr = 4 waves in 2x2, global_load_lds staging.
// LDS layout As[kc][m][8]: element A[m][k] at As[(k>>3)*1024 + m*8 + (k&7)].
// ---------------------------------------------------------------------------
__global__ __launch_bounds__(256) void proj_mfma(
    const unsigned short* __restrict__ xb, const unsigned short* __restrict__ Wb,
    unsigned short* __restrict__ C)
{
    __shared__ unsigned short As[4096];   // 4 kc * 128 m * 8
    __shared__ unsigned short Bs[4096];
    const int m0 = blockIdx.x * 128;
    const int n0 = blockIdx.y * 128;
    const unsigned short* Wbase = Wb + (size_t)(n0 >> 10) * HH * HH;
    const int nw0 = n0 & (HH - 1);
    const int tid = threadIdx.x;
    const int wave = tid >> 6, lane = tid & 63;
    const int quad = lane >> 4, l15 = lane & 15;
    const int wm = wave >> 1, wn = wave & 1;

    f32x4 acc[4][4];
    #pragma unroll
    for (int i = 0; i < 4; ++i)
        #pragma unroll
        for (int j = 0; j < 4; ++j) acc[i][j] = (f32x4){0.f, 0.f, 0.f, 0.f};

    for (int k0 = 0; k0 < HH; k0 += 32) {
        __syncthreads();
        #pragma unroll
        for (int q = 0; q < 2; ++q) {
            const int chunk = (wave * 2 + q) * 64 + lane;   // 0..511
            const int kc = chunk >> 7, mrow = chunk & 127;
            gload_lds16(xb    + (size_t)(m0  + mrow) * HH + k0 + kc * 8, As + chunk * 8);
            gload_lds16(Wbase + (size_t)(nw0 + mrow) * HH + k0 + kc * 8, Bs + chunk * 8);
        }
        __syncthreads();
        short8 af[4], bf[4];
        #pragma unroll
        for (int i = 0; i < 4; ++i)
            af[i] = *(const short8*)&As[(quad * 128 + wm * 64 + i * 16 + l15) * 8];
        #pragma unroll
        for (int j = 0; j < 4; ++j)
            bf[j] = *(const short8*)&Bs[(quad * 128 + wn * 64 + j * 16 + l15) * 8];
        #pragma unroll
        for (int i = 0; i < 4; ++i)
            #pragma unroll
            for (int j = 0; j < 4; ++j)
                acc[i][j] = __builtin_amdgcn_mfma_f32_16x16x32_bf16(af[i], bf[j], acc[i][j], 0, 0, 0);
    }
    // epilogue: C/D layout row=quad*4+reg, col=lane&15 (m89-verified)
    #pragma unroll
    for (int i = 0; i < 4; ++i)
        #pragma unroll
        for (int j = 0; j < 4; ++j) {
            const int col = n0 + wn * 64 + j * 16 + l15;
            #pragma unroll
            for (int r = 0; r < 4; ++r) {
                const int row = m0 + wm * 64 + i * 16 + quad * 4 + r;
                C[(size_t)row * N3 + col] = f2bf(acc[i][j][r]);
            }
        }
}

// ---------------------------------------------------------------------------
// Attention pass 1: linv[b,h,t] = 1 / sum_s exp(S[t,s]/8).
// Block = 64 t-rows x (b,h); 4 waves split s into 512-stripes; QK^T via MFMA
// with fragments loaded DIRECTLY from global (no LDS in hot loop).
// ---------------------------------------------------------------------------
__global__ __launch_bounds__(256) void attn_pass1(
    const unsigned short* __restrict__ qkv, float* __restrict__ linv)
{
    const int t0 = blockIdx.x * 64;
    const int h = blockIdx.y, b = blockIdx.z;
    const int tid = threadIdx.x;
    const int wave = tid >> 6, lane = tid & 63;
    const int quad = lane >> 4, l15 = lane & 15;
    __shared__ float red[4][64];

    const size_t qbase = (size_t)(b * TT) * N3 + h * DHH;       // Q region
    const size_t kbase = qbase + HH;                            // K region

    short8 aq[4][2];   // A-frag: A[m=l15][k=quad*8+j (+32c)]
    #pragma unroll
    for (int i = 0; i < 4; ++i)
        #pragma unroll
        for (int c = 0; c < 2; ++c)
            aq[i][c] = *(const short8*)&qkv[qbase + (size_t)(t0 + i * 16 + l15) * N3 + quad * 8 + c * 32];

    float rs[4][4];
    #pragma unroll
    for (int i = 0; i < 4; ++i)
        #pragma unroll
        for (int r = 0; r < 4; ++r) rs[i][r] = 0.f;

    for (int sstep = 0; sstep < 32; ++sstep) {
        const int s = wave * 512 + sstep * 16;
        const size_t krow = kbase + (size_t)(s + l15) * N3 + quad * 8;
        short8 bq0 = *(const short8*)&qkv[krow];
        short8 bq1 = *(const short8*)&qkv[krow + 32];
        #pragma unroll
        for (int i = 0; i < 4; ++i) {
            f32x4 c = (f32x4){0.f, 0.f, 0.f, 0.f};
            c = __builtin_amdgcn_mfma_f32_16x16x32_bf16(aq[i][0], bq0, c, 0, 0, 0);
            c = __builtin_amdgcn_mfma_f32_16x16x32_bf16(aq[i][1], bq1, c, 0, 0, 0);
            #pragma unroll
            for (int r = 0; r < 4; ++r) rs[i][r] += __expf(c[r] * 0.125f);
        }
    }
    // reduce across the 16 columns (lane bits 0..3)
    #pragma unroll
    for (int off = 1; off < 16; off <<= 1)
        #pragma unroll
        for (int i = 0; i < 4; ++i)
            #pragma unroll
            for (int r = 0; r < 4; ++r) rs[i][r] += __shfl_xor(rs[i][r], off);
    if (l15 == 0)
        #pragma unroll
        for (int i = 0; i < 4; ++i)
            #pragma unroll
            for (int r = 0; r < 4; ++r) red[wave][i * 16 + quad * 4 + r] = rs[i][r];
    __syncthreads();
    if (tid < 64) {
        const float l = red[0][tid] + red[1][tid] + red[2][tid] + red[3][tid];
        linv[(size_t)(b * NHH + h) * TT + t0 + tid] = 1.0f / l;
    }
}

// ---------------------------------------------------------------------------
// Attention pass 2: a[b,h,s] += (1/T) sum_t exp(S[t,s]/8) * linv[t]
// ---------------------------------------------------------------------------
__global__ __launch_bounds__(256) void attn_pass2(
    const unsigned short* __restrict__ qkv, const float* __restrict__ linv,
    float* __restrict__ a)
{
    const int t0 = blockIdx.x * 64;
    const int h = blockIdx.y, b = blockIdx.z;
    const int tid = threadIdx.x;
    const int wave = tid >> 6, lane = tid & 63;
    const int quad = lane >> 4, l15 = lane & 15;
    const int bh = b * NHH + h;
    __shared__ float lt[64];

    if (tid < 64) lt[tid] = linv[(size_t)bh * TT + t0 + tid];

    const size_t qbase = (size_t)(b * TT) * N3 + h * DHH;
    const size_t kbase = qbase + HH;

    short8 aq[4][2];
    #pragma unroll
    for (int i = 0; i < 4; ++i)
        #pragma unroll
        for (int c = 0; c < 2; ++c)
            aq[i][c] = *(const short8*)&qkv[qbase + (size_t)(t0 + i * 16 + l15) * N3 + quad * 8 + c * 32];

    __syncthreads();
    float lrv[4][4];
    #pragma unroll
    for (int i = 0; i < 4; ++i)
        #pragma unroll
        for (int r = 0; r < 4; ++r) lrv[i][r] = lt[i * 16 + quad * 4 + r];

    for (int sstep = 0; sstep < 32; ++sstep) {
        const int s = wave * 512 + sstep * 16;
        const size_t krow = kbase + (size_t)(s + l15) * N3 + quad * 8;
        short8 bq0 = *(const short8*)&qkv[krow];
        short8 bq1 = *(const short8*)&qkv[krow + 32];
        float cs = 0.f;
        #pragma unroll
        for (int i = 0; i < 4; ++i) {
            f32x4 c = (f32x4){0.f, 0.f, 0.f, 0.f};
            c = __builtin_amdgcn_mfma_f32_16x16x32_bf16(aq[i][0], bq0, c, 0, 0, 0);
            c = __builtin_amdgcn_mfma_f32_16x16x32_bf16(aq[i][1], bq1, c, 0, 0, 0);
            #pragma unroll
            for (int r = 0; r < 4; ++r) cs += __expf(c[r] * 0.125f) * lrv[i][r];
        }
        cs += __shfl_xor(cs, 16);
        cs += __shfl_xor(cs, 32);
        if (lane < 16)
            atomicAdd(&a[(size_t)bh * TT + s + l15], cs * (1.0f / TT));
    }
}

// ---------------------------------------------------------------------------
// cm[b, h*64+d] += sum_{s in sblock} a[b,h,s] * V[b,s,h*64+d]
// ---------------------------------------------------------------------------
__global__ __launch_bounds__(256) void ctx_mean(
    const unsigned short* __restrict__ qkv, const float* __restrict__ a,
    float* __restrict__ cm)
{
    const int h = blockIdx.x, b = blockIdx.y, sb = blockIdx.z;
    const int tid = threadIdx.x;
    const int d = tid & 63, sg = tid >> 6;
    __shared__ float red[4][64];
    float part = 0.f;
    for (int s = sb * 256 + sg; s < sb * 256 + 256; s += 4) {
        const float av = a[(size_t)(b * NHH + h) * TT + s];
        part += av * bf2f(qkv[(size_t)(b * TT + s) * N3 + 2 * HH + h * DHH + d]);
    }
    red[sg][d] = part;
    __syncthreads();
    if (tid < 64)
        atomicAdd(&cm[b * HH + h * DHH + tid],
                  red[0][tid] + red[1][tid] + red[2][tid] + red[3][tid]);
}

// ---------------------------------------------------------------------------
// out[b][j] = bo[j] + sum_k cm[b][k] * Wo[j][k]
// ---------------------------------------------------------------------------
__global__ __launch_bounds__(256) void out_proj(
    const float* __restrict__ cm, const float* __restrict__ Wo,
    const float* __restrict__ bo, float* __restrict__ out)
{
    const int b = blockIdx.y;
    const int jb = blockIdx.x;
    const int tid = threadIdx.x;
    const int j = jb * 64 + (tid >> 2);
    const int kg = tid & 3;
    __shared__ float cs[HH];
    for (int k = tid; k < HH; k += 256) cs[k] = cm[b * HH + k];
    __syncthreads();
    float acc = 0.f;
    const float* wrow = &Wo[(size_t)j * HH];
    #pragma unroll 8
    for (int i = 0; i < 64; ++i) {
        const int k = kg * 256 + i * 4;
        float4 w4 = *(const float4*)&wrow[k];
        acc += w4.x * cs[k] + w4.y * cs[k+1] + w4.z * cs[k+2] + w4.w * cs[k+3];
    }
    acc += __shfl_down(acc, 2, 4);
    acc += __shfl_down(acc, 1, 4);
    if (kg == 0) out[b * HH + j] = acc + bo[j];
}

// ---------------------------------------------------------------------------
extern "C" void kernel_launch(void* const* d_in, const int* in_sizes, int n_in,
                              void* d_out, int out_size, void* d_ws, size_t ws_size,
                              hipStream_t stream) {
    const float* x  = (const float*)d_in[0];
    const float* Wq = (const float*)d_in[1];
    const float* Wk = (const float*)d_in[2];
    const float* Wv = (const float*)d_in[3];
    const float* Wo = (const float*)d_in[4];
    const float* bo = (const float*)d_in[5];
    float* out = (float*)d_out;

    char* ws = (char*)d_ws;
    unsigned short* qkv = (unsigned short*)ws;                 // 50.33 MB
    ws += (size_t)MM * N3 * 2;
    unsigned short* xb = (unsigned short*)ws;                  // 16.78 MB
    ws += (size_t)MM * HH * 2;
    unsigned short* Wb = (unsigned short*)ws;                  // 6.29 MB
    ws += (size_t)3 * HH * HH * 2;
    float* linv = (float*)ws;                                  // 0.52 MB
    ws += (size_t)BB * NHH * TT * 4;
    float* a = (float*)ws;                                     // 0.52 MB
    ws += (size_t)BB * NHH * TT * 4;
    float* cm = (float*)ws;                                    // 16 KB

    hipMemsetAsync(a, 0, (size_t)(BB * NHH * TT + BB * HH) * 4, stream);  // a + cm

    cvt_bf16<<<2048, 256, 0, stream>>>(x,  xb,          MM * HH / 4);
    cvt_bf16<<<512,  256, 0, stream>>>(Wq, Wb,          HH * HH / 4);
    cvt_bf16<<<512,  256, 0, stream>>>(Wk, Wb + HH*HH,  HH * HH / 4);
    cvt_bf16<<<512,  256, 0, stream>>>(Wv, Wb + 2*HH*HH, HH * HH / 4);

    proj_mfma <<<dim3(64, 24),      256, 0, stream>>>(xb, Wb, qkv);
    attn_pass1<<<dim3(32, NHH, BB), 256, 0, stream>>>(qkv, linv);
    attn_pass2<<<dim3(32, NHH, BB), 256, 0, stream>>>(qkv, linv, a);
    ctx_mean  <<<dim3(NHH, BB, 8),  256, 0, stream>>>(qkv, a, cm);
    out_proj  <<<dim3(16, BB),      256, 0, stream>>>(cm, Wo, bo, out);
}

// Round 3
// 335.549 us; speedup vs baseline: 5.0297x; 1.2488x over previous
//
#include <hip/hip_runtime.h>
#include <hip/hip_bf16.h>
#include <cstdint>

#define BB   4
#define TT   2048
#define HH   1024
#define NHH  16
#define DHH  64
#define MM   (BB*TT)      // 8192
#define N3   (3*HH)       // 3072

typedef __attribute__((ext_vector_type(8))) short short8;   // 8 bf16 = 4 VGPR
typedef __attribute__((ext_vector_type(4))) float f32x4;

__device__ __forceinline__ float bf2f(unsigned short u) {
    return __uint_as_float(((uint32_t)u) << 16);
}
__device__ __forceinline__ unsigned short f2bf(float f) {
    uint32_t u = __float_as_uint(f);
    return (unsigned short)((u + 0x7fffu + ((u >> 16) & 1u)) >> 16);  // RNE
}
__device__ __forceinline__ void gload_lds16(const unsigned short* g, unsigned short* l) {
    __builtin_amdgcn_global_load_lds(
        (const __attribute__((address_space(1))) uint32_t*)g,
        (__attribute__((address_space(3))) uint32_t*)l, 16, 0, 0);
}

// ---------------------------------------------------------------------------
// f32 -> bf16 bulk convert
// ---------------------------------------------------------------------------
__global__ __launch_bounds__(256) void cvt_bf16(
    const float* __restrict__ src, unsigned short* __restrict__ dst, int n4)
{
    int i = blockIdx.x * 256 + threadIdx.x;
    const int stride = gridDim.x * 256;
    for (; i < n4; i += stride) {
        float4 v = ((const float4*)src)[i];
        ushort4 o;
        o.x = f2bf(v.x); o.y = f2bf(v.y); o.z = f2bf(v.z); o.w = f2bf(v.w);
        ((ushort4*)dst)[i] = o;
    }
}

// ---------------------------------------------------------------------------
// QKV projection: C[M][3H] bf16 = xb @ Wb[sel]^T (MFMA 16x16x32, 128x128 tile)
// Q slab (cols 0..1023) is pre-scaled by 0.125 (= 1/sqrt(DH)) so the
// attention kernel's exp argument needs no extra multiply.
// ---------------------------------------------------------------------------
__global__ __launch_bounds__(256) void proj_mfma(
    const unsigned short* __restrict__ xb, const unsigned short* __restrict__ Wb,
    unsigned short* __restrict__ C)
{
    __shared__ unsigned short As[4096];   // 4 kc * 128 m * 8
    __shared__ unsigned short Bs[4096];
    const int m0 = blockIdx.x * 128;
    const int n0 = blockIdx.y * 128;
    const unsigned short* Wbase = Wb + (size_t)(n0 >> 10) * HH * HH;
    const int nw0 = n0 & (HH - 1);
    const int tid = threadIdx.x;
    const int wave = tid >> 6, lane = tid & 63;
    const int quad = lane >> 4, l15 = lane & 15;
    const int wm = wave >> 1, wn = wave & 1;

    f32x4 acc[4][4];
    #pragma unroll
    for (int i = 0; i < 4; ++i)
        #pragma unroll
        for (int j = 0; j < 4; ++j) acc[i][j] = (f32x4){0.f, 0.f, 0.f, 0.f};

    for (int k0 = 0; k0 < HH; k0 += 32) {
        __syncthreads();
        #pragma unroll
        for (int q = 0; q < 2; ++q) {
            const int chunk = (wave * 2 + q) * 64 + lane;   // 0..511
            const int kc = chunk >> 7, mrow = chunk & 127;
            gload_lds16(xb    + (size_t)(m0  + mrow) * HH + k0 + kc * 8, As + chunk * 8);
            gload_lds16(Wbase + (size_t)(nw0 + mrow) * HH + k0 + kc * 8, Bs + chunk * 8);
        }
        __syncthreads();
        short8 af[4], bf[4];
        #pragma unroll
        for (int i = 0; i < 4; ++i)
            af[i] = *(const short8*)&As[(quad * 128 + wm * 64 + i * 16 + l15) * 8];
        #pragma unroll
        for (int j = 0; j < 4; ++j)
            bf[j] = *(const short8*)&Bs[(quad * 128 + wn * 64 + j * 16 + l15) * 8];
        #pragma unroll
        for (int i = 0; i < 4; ++i)
            #pragma unroll
            for (int j = 0; j < 4; ++j)
                acc[i][j] = __builtin_amdgcn_mfma_f32_16x16x32_bf16(af[i], bf[j], acc[i][j], 0, 0, 0);
    }
    const float cscale = (n0 < HH) ? 0.125f : 1.0f;   // fold 1/sqrt(DH) into Q
    #pragma unroll
    for (int i = 0; i < 4; ++i)
        #pragma unroll
        for (int j = 0; j < 4; ++j) {
            const int col = n0 + wn * 64 + j * 16 + l15;
            #pragma unroll
            for (int r = 0; r < 4; ++r) {
                const int row = m0 + wm * 64 + i * 16 + quad * 4 + r;
                C[(size_t)row * N3 + col] = f2bf(acc[i][j][r] * cscale);
            }
        }
}

// ---------------------------------------------------------------------------
// Fused attention: per (b,h,128-t-block):
//   phase 1: l_t = sum_s exp(S[t,s]);  linv[t] = 1/(l_t * T)   (LDS)
//   phase 2: a[b,h,s] += sum_t exp(S[t,s]) * linv[t]           (atomics)
// K-fragments register-prefetched one sstep ahead; no LDS in the hot loop.
// ---------------------------------------------------------------------------
__global__ __launch_bounds__(256) void attn_fused(
    const unsigned short* __restrict__ qkv, float* __restrict__ a)
{
    const int t0 = blockIdx.x * 128;   // 16 t-blocks
    const int h = blockIdx.y, b = blockIdx.z;
    const int tid = threadIdx.x;
    const int wave = tid >> 6, lane = tid & 63;
    const int quad = lane >> 4, l15 = lane & 15;
    const int bh = b * NHH + h;
    __shared__ float red[4][128];
    __shared__ float linv[128];

    const size_t qbase = (size_t)(b * TT) * N3 + h * DHH;
    const size_t kbase = qbase + HH;

    // A-frags: 8 row-groups of 16 t, k split 0..31 / 32..63
    short8 aq[8][2];
    #pragma unroll
    for (int i = 0; i < 8; ++i)
        #pragma unroll
        for (int c = 0; c < 2; ++c)
            aq[i][c] = *(const short8*)&qkv[qbase + (size_t)(t0 + i * 16 + l15) * N3 + quad * 8 + c * 32];

    // ---- phase 1: row sums ----
    float rs[8][4];
    #pragma unroll
    for (int i = 0; i < 8; ++i)
        #pragma unroll
        for (int r = 0; r < 4; ++r) rs[i][r] = 0.f;

    const size_t kstripe = kbase + (size_t)(wave * 512 + l15) * N3 + quad * 8;
    short8 nb0 = *(const short8*)&qkv[kstripe];
    short8 nb1 = *(const short8*)&qkv[kstripe + 32];
    for (int sstep = 0; sstep < 32; ++sstep) {
        const short8 bq0 = nb0, bq1 = nb1;
        if (sstep < 31) {
            const size_t krow = kstripe + (size_t)((sstep + 1) * 16) * N3;
            nb0 = *(const short8*)&qkv[krow];
            nb1 = *(const short8*)&qkv[krow + 32];
        }
        #pragma unroll
        for (int i = 0; i < 8; ++i) {
            f32x4 c = (f32x4){0.f, 0.f, 0.f, 0.f};
            c = __builtin_amdgcn_mfma_f32_16x16x32_bf16(aq[i][0], bq0, c, 0, 0, 0);
            c = __builtin_amdgcn_mfma_f32_16x16x32_bf16(aq[i][1], bq1, c, 0, 0, 0);
            #pragma unroll
            for (int r = 0; r < 4; ++r) rs[i][r] += __expf(c[r]);
        }
    }
    #pragma unroll
    for (int off = 1; off < 16; off <<= 1)
        #pragma unroll
        for (int i = 0; i < 8; ++i)
            #pragma unroll
            for (int r = 0; r < 4; ++r) rs[i][r] += __shfl_xor(rs[i][r], off);
    if (l15 == 0)
        #pragma unroll
        for (int i = 0; i < 8; ++i)
            #pragma unroll
            for (int r = 0; r < 4; ++r) red[wave][i * 16 + quad * 4 + r] = rs[i][r];
    __syncthreads();
    if (tid < 128) {
        const float l = red[0][tid] + red[1][tid] + red[2][tid] + red[3][tid];
        linv[tid] = 1.0f / (l * (float)TT);
    }
    __syncthreads();

    // ---- phase 2: column sums ----
    float lrv[8][4];
    #pragma unroll
    for (int i = 0; i < 8; ++i)
        #pragma unroll
        for (int r = 0; r < 4; ++r) lrv[i][r] = linv[i * 16 + quad * 4 + r];

    nb0 = *(const short8*)&qkv[kstripe];
    nb1 = *(const short8*)&qkv[kstripe + 32];
    for (int sstep = 0; sstep < 32; ++sstep) {
        const short8 bq0 = nb0, bq1 = nb1;
        if (sstep < 31) {
            const size_t krow = kstripe + (size_t)((sstep + 1) * 16) * N3;
            nb0 = *(const short8*)&qkv[krow];
            nb1 = *(const short8*)&qkv[krow + 32];
        }
        float cs = 0.f;
        #pragma unroll
        for (int i = 0; i < 8; ++i) {
            f32x4 c = (f32x4){0.f, 0.f, 0.f, 0.f};
            c = __builtin_amdgcn_mfma_f32_16x16x32_bf16(aq[i][0], bq0, c, 0, 0, 0);
            c = __builtin_amdgcn_mfma_f32_16x16x32_bf16(aq[i][1], bq1, c, 0, 0, 0);
            #pragma unroll
            for (int r = 0; r < 4; ++r) cs += __expf(c[r]) * lrv[i][r];
        }
        cs += __shfl_xor(cs, 16);
        cs += __shfl_xor(cs, 32);
        if (lane < 16)
            atomicAdd(&a[(size_t)bh * TT + wave * 512 + sstep * 16 + l15], cs);
    }
}

// ---------------------------------------------------------------------------
// cm[b, h*64+d] += sum_{s in sblock} a[b,h,s] * V[b,s,h*64+d]
// ---------------------------------------------------------------------------
__global__ __launch_bounds__(256) void ctx_mean(
    const unsigned short* __restrict__ qkv, const float* __restrict__ a,
    float* __restrict__ cm)
{
    const int h = blockIdx.x, b = blockIdx.y, sb = blockIdx.z;
    const int tid = threadIdx.x;
    const int d = tid & 63, sg = tid >> 6;
    __shared__ float red[4][64];
    float part = 0.f;
    for (int s = sb * 256 + sg; s < sb * 256 + 256; s += 4) {
        const float av = a[(size_t)(b * NHH + h) * TT + s];
        part += av * bf2f(qkv[(size_t)(b * TT + s) * N3 + 2 * HH + h * DHH + d]);
    }
    red[sg][d] = part;
    __syncthreads();
    if (tid < 64)
        atomicAdd(&cm[b * HH + h * DHH + tid],
                  red[0][tid] + red[1][tid] + red[2][tid] + red[3][tid]);
}

// ---------------------------------------------------------------------------
// out[b][j] = bo[j] + sum_k cm[b][k] * Wo[j][k]
// ---------------------------------------------------------------------------
__global__ __launch_bounds__(256) void out_proj(
    const float* __restrict__ cm, const float* __restrict__ Wo,
    const float* __restrict__ bo, float* __restrict__ out)
{
    const int b = blockIdx.y;
    const int jb = blockIdx.x;
    const int tid = threadIdx.x;
    const int j = jb * 64 + (tid >> 2);
    const int kg = tid & 3;
    __shared__ float cs[HH];
    for (int k = tid; k < HH; k += 256) cs[k] = cm[b * HH + k];
    __syncthreads();
    float acc = 0.f;
    const float* wrow = &Wo[(size_t)j * HH];
    #pragma unroll 8
    for (int i = 0; i < 64; ++i) {
        const int k = kg * 256 + i * 4;
        float4 w4 = *(const float4*)&wrow[k];
        acc += w4.x * cs[k] + w4.y * cs[k+1] + w4.z * cs[k+2] + w4.w * cs[k+3];
    }
    acc += __shfl_down(acc, 2, 4);
    acc += __shfl_down(acc, 1, 4);
    if (kg == 0) out[b * HH + j] = acc + bo[j];
}

// ---------------------------------------------------------------------------
extern "C" void kernel_launch(void* const* d_in, const int* in_sizes, int n_in,
                              void* d_out, int out_size, void* d_ws, size_t ws_size,
                              hipStream_t stream) {
    const float* x  = (const float*)d_in[0];
    const float* Wq = (const float*)d_in[1];
    const float* Wk = (const float*)d_in[2];
    const float* Wv = (const float*)d_in[3];
    const float* Wo = (const float*)d_in[4];
    const float* bo = (const float*)d_in[5];
    float* out = (float*)d_out;

    char* ws = (char*)d_ws;
    unsigned short* qkv = (unsigned short*)ws;                 // 50.33 MB
    ws += (size_t)MM * N3 * 2;
    unsigned short* xb = (unsigned short*)ws;                  // 16.78 MB
    ws += (size_t)MM * HH * 2;
    unsigned short* Wb = (unsigned short*)ws;                  // 6.29 MB
    ws += (size_t)3 * HH * HH * 2;
    float* a = (float*)ws;                                     // 0.52 MB
    ws += (size_t)BB * NHH * TT * 4;
    float* cm = (float*)ws;                                    // 16 KB

    hipMemsetAsync(a, 0, (size_t)(BB * NHH * TT + BB * HH) * 4, stream);  // a + cm

    cvt_bf16<<<2048, 256, 0, stream>>>(x,  xb,           MM * HH / 4);
    cvt_bf16<<<512,  256, 0, stream>>>(Wq, Wb,           HH * HH / 4);
    cvt_bf16<<<512,  256, 0, stream>>>(Wk, Wb + HH*HH,   HH * HH / 4);
    cvt_bf16<<<512,  256, 0, stream>>>(Wv, Wb + 2*HH*HH, HH * HH / 4);

    proj_mfma <<<dim3(64, 24),      256, 0, stream>>>(xb, Wb, qkv);
    attn_fused<<<dim3(16, NHH, BB), 256, 0, stream>>>(qkv, a);
    ctx_mean  <<<dim3(NHH, BB, 8),  256, 0, stream>>>(qkv, a, cm);
    out_proj  <<<dim3(16, BB),      256, 0, stream>>>(cm, Wo, bo, out);
}

// Round 4
// 321.177 us; speedup vs baseline: 5.2548x; 1.0447x over previous
//
#include <hip/hip_runtime.h>
#include <hip/hip_bf16.h>
#include <cstdint>

#define BB   4
#define TT   2048
#define HH   1024
#define NHH  16
#define DHH  64
#define MM   (BB*TT)      // 8192
#define N3   (3*HH)       // 3072

typedef __attribute__((ext_vector_type(8))) short short8;   // 8 bf16 = 4 VGPR
typedef __attribute__((ext_vector_type(4))) float f32x4;

#if __has_builtin(__builtin_amdgcn_exp2f)
#define EXP2F(x) __builtin_amdgcn_exp2f(x)
#else
#define EXP2F(x) exp2f(x)
#endif

// Q pre-scale: (1/sqrt(DH)) * log2(e)  so scores are in log2 domain
#define QSCALE 0.1803368801111204f

__device__ __forceinline__ float bf2f(unsigned short u) {
    return __uint_as_float(((uint32_t)u) << 16);
}
__device__ __forceinline__ unsigned short f2bf(float f) {
    uint32_t u = __float_as_uint(f);
    return (unsigned short)((u + 0x7fffu + ((u >> 16) & 1u)) >> 16);  // RNE
}
__device__ __forceinline__ void gload_lds16(const unsigned short* g, unsigned short* l) {
    __builtin_amdgcn_global_load_lds(
        (const __attribute__((address_space(1))) uint32_t*)g,
        (__attribute__((address_space(3))) uint32_t*)l, 16, 0, 0);
}

// ---------------------------------------------------------------------------
// f32 -> bf16 bulk convert (x)
// ---------------------------------------------------------------------------
__global__ __launch_bounds__(256) void cvt_bf16(
    const float* __restrict__ src, unsigned short* __restrict__ dst, int n4)
{
    int i = blockIdx.x * 256 + threadIdx.x;
    const int stride = gridDim.x * 256;
    for (; i < n4; i += stride) {
        float4 v = ((const float4*)src)[i];
        ushort4 o;
        o.x = f2bf(v.x); o.y = f2bf(v.y); o.z = f2bf(v.z); o.w = f2bf(v.w);
        ((ushort4*)dst)[i] = o;
    }
}

// all three weight matrices in one launch (blockIdx.y selects)
__global__ __launch_bounds__(256) void cvt_w3(
    const float* __restrict__ Wq, const float* __restrict__ Wk,
    const float* __restrict__ Wv, unsigned short* __restrict__ Wb)
{
    const float* src = (blockIdx.y == 0) ? Wq : (blockIdx.y == 1 ? Wk : Wv);
    unsigned short* dst = Wb + (size_t)blockIdx.y * HH * HH;
    const int n4 = HH * HH / 4;
    int i = blockIdx.x * 256 + threadIdx.x;
    const int stride = gridDim.x * 256;
    for (; i < n4; i += stride) {
        float4 v = ((const float4*)src)[i];
        ushort4 o;
        o.x = f2bf(v.x); o.y = f2bf(v.y); o.z = f2bf(v.z); o.w = f2bf(v.w);
        ((ushort4*)dst)[i] = o;
    }
}

// ---------------------------------------------------------------------------
// QKV projection (MFMA 16x16x32, 128x128 tile, BK=32, global_load_lds).
// Epilogue writes packed per-head tensors qp/kp/vp[b][h][t][64] (bf16);
// Q slab pre-scaled by QSCALE so attention uses native exp2.
// ---------------------------------------------------------------------------
__global__ __launch_bounds__(256) void proj_mfma(
    const unsigned short* __restrict__ xb, const unsigned short* __restrict__ Wb,
    unsigned short* __restrict__ qp, unsigned short* __restrict__ kp,
    unsigned short* __restrict__ vp)
{
    __shared__ unsigned short As[4096];   // 4 kc * 128 m * 8
    __shared__ unsigned short Bs[4096];
    const int m0 = blockIdx.x * 128;
    const int n0 = blockIdx.y * 128;
    const int sel = n0 >> 10;
    const unsigned short* Wbase = Wb + (size_t)sel * HH * HH;
    const int nw0 = n0 & (HH - 1);
    const int tid = threadIdx.x;
    const int wave = tid >> 6, lane = tid & 63;
    const int quad = lane >> 4, l15 = lane & 15;
    const int wm = wave >> 1, wn = wave & 1;

    f32x4 acc[4][4];
    #pragma unroll
    for (int i = 0; i < 4; ++i)
        #pragma unroll
        for (int j = 0; j < 4; ++j) acc[i][j] = (f32x4){0.f, 0.f, 0.f, 0.f};

    for (int k0 = 0; k0 < HH; k0 += 32) {
        __syncthreads();
        #pragma unroll
        for (int q = 0; q < 2; ++q) {
            const int chunk = (wave * 2 + q) * 64 + lane;   // 0..511
            const int kc = chunk >> 7, mrow = chunk & 127;
            gload_lds16(xb    + (size_t)(m0  + mrow) * HH + k0 + kc * 8, As + chunk * 8);
            gload_lds16(Wbase + (size_t)(nw0 + mrow) * HH + k0 + kc * 8, Bs + chunk * 8);
        }
        __syncthreads();
        short8 af[4], bf[4];
        #pragma unroll
        for (int i = 0; i < 4; ++i)
            af[i] = *(const short8*)&As[(quad * 128 + wm * 64 + i * 16 + l15) * 8];
        #pragma unroll
        for (int j = 0; j < 4; ++j)
            bf[j] = *(const short8*)&Bs[(quad * 128 + wn * 64 + j * 16 + l15) * 8];
        #pragma unroll
        for (int i = 0; i < 4; ++i)
            #pragma unroll
            for (int j = 0; j < 4; ++j)
                acc[i][j] = __builtin_amdgcn_mfma_f32_16x16x32_bf16(af[i], bf[j], acc[i][j], 0, 0, 0);
    }
    unsigned short* outp = (sel == 0) ? qp : (sel == 1 ? kp : vp);
    const float cscale = (sel == 0) ? QSCALE : 1.0f;
    #pragma unroll
    for (int i = 0; i < 4; ++i)
        #pragma unroll
        for (int j = 0; j < 4; ++j) {
            const int col = n0 + wn * 64 + j * 16 + l15;
            const int hh2 = (col >> 6) & (NHH - 1);
            const int dd  = col & (DHH - 1);
            #pragma unroll
            for (int r = 0; r < 4; ++r) {
                const int row = m0 + wm * 64 + i * 16 + quad * 4 + r;
                const int bb2 = row >> 11, tt2 = row & (TT - 1);
                outp[((size_t)(bb2 * NHH + hh2) * TT + tt2) * DHH + dd] =
                    f2bf(acc[i][j][r] * cscale);
            }
        }
}

// ---------------------------------------------------------------------------
// Fused attention over packed layout:
//   phase 1: l_t = sum_s exp2(S[t,s]);  linv[t] = 1/(l_t*T)
//   phase 2: a[b,h,s] += sum_t exp2(S[t,s]) * linv[t]   (atomics)
// K fragments are 2KB contiguous streams, prefetched 2 ssteps ahead.
// ---------------------------------------------------------------------------
__global__ __launch_bounds__(256) void attn_fused(
    const unsigned short* __restrict__ qp, const unsigned short* __restrict__ kp,
    float* __restrict__ a)
{
    const int t0 = blockIdx.x * 128;   // 16 t-blocks
    const int h = blockIdx.y, b = blockIdx.z;
    const int bh = b * NHH + h;
    const int tid = threadIdx.x;
    const int wave = tid >> 6, lane = tid & 63;
    const int quad = lane >> 4, l15 = lane & 15;
    __shared__ float red[4][128];
    __shared__ float linv[128];

    const unsigned short* q = qp + (size_t)bh * TT * DHH;
    const unsigned short* kptr =
        kp + (size_t)bh * TT * DHH + (size_t)(wave * 512 + l15) * DHH + quad * 8;

    // A-frags: 8 row-groups of 16 t; k split 0..31 / 32..63
    short8 aq[8][2];
    #pragma unroll
    for (int i = 0; i < 8; ++i)
        #pragma unroll
        for (int c = 0; c < 2; ++c)
            aq[i][c] = *(const short8*)&q[(size_t)(t0 + i * 16 + l15) * DHH + quad * 8 + c * 32];

#define KLD(ss, c) (*(const short8*)(kptr + (size_t)(ss) * 16 * DHH + (c) * 32))

    // ---- phase 1: row sums ----
    float rs[8][4];
    #pragma unroll
    for (int i = 0; i < 8; ++i)
        #pragma unroll
        for (int r = 0; r < 4; ++r) rs[i][r] = 0.f;

    {
        short8 c0a = KLD(0, 0), c0b = KLD(0, 1);
        short8 c1a = KLD(1, 0), c1b = KLD(1, 1);
        for (int ss = 0; ss < 32; ++ss) {
            const short8 ba = c0a, bb = c0b;
            c0a = c1a; c0b = c1b;
            if (ss < 30) { c1a = KLD(ss + 2, 0); c1b = KLD(ss + 2, 1); }
            #pragma unroll
            for (int i = 0; i < 8; ++i) {
                f32x4 c = (f32x4){0.f, 0.f, 0.f, 0.f};
                c = __builtin_amdgcn_mfma_f32_16x16x32_bf16(aq[i][0], ba, c, 0, 0, 0);
                c = __builtin_amdgcn_mfma_f32_16x16x32_bf16(aq[i][1], bb, c, 0, 0, 0);
                #pragma unroll
                for (int r = 0; r < 4; ++r) rs[i][r] += EXP2F(c[r]);
            }
        }
    }
    #pragma unroll
    for (int off = 1; off < 16; off <<= 1)
        #pragma unroll
        for (int i = 0; i < 8; ++i)
            #pragma unroll
            for (int r = 0; r < 4; ++r) rs[i][r] += __shfl_xor(rs[i][r], off);
    if (l15 == 0)
        #pragma unroll
        for (int i = 0; i < 8; ++i)
            #pragma unroll
            for (int r = 0; r < 4; ++r) red[wave][i * 16 + quad * 4 + r] = rs[i][r];
    __syncthreads();
    if (tid < 128) {
        const float l = red[0][tid] + red[1][tid] + red[2][tid] + red[3][tid];
        linv[tid] = 1.0f / (l * (float)TT);
    }
    __syncthreads();

    // ---- phase 2: column sums ----
    float lrv[8][4];
    #pragma unroll
    for (int i = 0; i < 8; ++i)
        #pragma unroll
        for (int r = 0; r < 4; ++r) lrv[i][r] = linv[i * 16 + quad * 4 + r];

    {
        short8 c0a = KLD(0, 0), c0b = KLD(0, 1);
        short8 c1a = KLD(1, 0), c1b = KLD(1, 1);
        for (int ss = 0; ss < 32; ++ss) {
            const short8 ba = c0a, bb = c0b;
            c0a = c1a; c0b = c1b;
            if (ss < 30) { c1a = KLD(ss + 2, 0); c1b = KLD(ss + 2, 1); }
            float cs = 0.f;
            #pragma unroll
            for (int i = 0; i < 8; ++i) {
                f32x4 c = (f32x4){0.f, 0.f, 0.f, 0.f};
                c = __builtin_amdgcn_mfma_f32_16x16x32_bf16(aq[i][0], ba, c, 0, 0, 0);
                c = __builtin_amdgcn_mfma_f32_16x16x32_bf16(aq[i][1], bb, c, 0, 0, 0);
                #pragma unroll
                for (int r = 0; r < 4; ++r) cs += EXP2F(c[r]) * lrv[i][r];
            }
            cs += __shfl_xor(cs, 16);
            cs += __shfl_xor(cs, 32);
            if (lane < 16)
                atomicAdd(&a[(size_t)bh * TT + wave * 512 + ss * 16 + l15], cs);
        }
    }
#undef KLD
}

// ---------------------------------------------------------------------------
// cm[b, h*64+d] += sum_{s in sblock} a[b,h,s] * V[b,h,s,d]   (packed V)
// ---------------------------------------------------------------------------
__global__ __launch_bounds__(256) void ctx_mean(
    const unsigned short* __restrict__ vp, const float* __restrict__ a,
    float* __restrict__ cm)
{
    const int h = blockIdx.x, b = blockIdx.y, sb = blockIdx.z;
    const int tid = threadIdx.x;
    const int d = tid & 63, sg = tid >> 6;
    const int bh = b * NHH + h;
    __shared__ float red[4][64];
    float part = 0.f;
    for (int s = sb * 256 + sg; s < sb * 256 + 256; s += 4) {
        const float av = a[(size_t)bh * TT + s];
        part += av * bf2f(vp[((size_t)bh * TT + s) * DHH + d]);
    }
    red[sg][d] = part;
    __syncthreads();
    if (tid < 64)
        atomicAdd(&cm[b * HH + h * DHH + tid],
                  red[0][tid] + red[1][tid] + red[2][tid] + red[3][tid]);
}

// ---------------------------------------------------------------------------
// out[b][j] = bo[j] + sum_k cm[b][k] * Wo[j][k]
// ---------------------------------------------------------------------------
__global__ __launch_bounds__(256) void out_proj(
    const float* __restrict__ cm, const float* __restrict__ Wo,
    const float* __restrict__ bo, float* __restrict__ out)
{
    const int b = blockIdx.y;
    const int jb = blockIdx.x;
    const int tid = threadIdx.x;
    const int j = jb * 64 + (tid >> 2);
    const int kg = tid & 3;
    __shared__ float cs[HH];
    for (int k = tid; k < HH; k += 256) cs[k] = cm[b * HH + k];
    __syncthreads();
    float acc = 0.f;
    const float* wrow = &Wo[(size_t)j * HH];
    #pragma unroll 8
    for (int i = 0; i < 64; ++i) {
        const int k = kg * 256 + i * 4;
        float4 w4 = *(const float4*)&wrow[k];
        acc += w4.x * cs[k] + w4.y * cs[k+1] + w4.z * cs[k+2] + w4.w * cs[k+3];
    }
    acc += __shfl_down(acc, 2, 4);
    acc += __shfl_down(acc, 1, 4);
    if (kg == 0) out[b * HH + j] = acc + bo[j];
}

// ---------------------------------------------------------------------------
extern "C" void kernel_launch(void* const* d_in, const int* in_sizes, int n_in,
                              void* d_out, int out_size, void* d_ws, size_t ws_size,
                              hipStream_t stream) {
    const float* x  = (const float*)d_in[0];
    const float* Wq = (const float*)d_in[1];
    const float* Wk = (const float*)d_in[2];
    const float* Wv = (const float*)d_in[3];
    const float* Wo = (const float*)d_in[4];
    const float* bo = (const float*)d_in[5];
    float* out = (float*)d_out;

    char* ws = (char*)d_ws;
    unsigned short* qp = (unsigned short*)ws;  ws += (size_t)MM * HH * 2;  // 16.78 MB
    unsigned short* kp = (unsigned short*)ws;  ws += (size_t)MM * HH * 2;
    unsigned short* vp = (unsigned short*)ws;  ws += (size_t)MM * HH * 2;
    unsigned short* xb = (unsigned short*)ws;  ws += (size_t)MM * HH * 2;
    unsigned short* Wb = (unsigned short*)ws;  ws += (size_t)3 * HH * HH * 2;
    float* a  = (float*)ws;                    ws += (size_t)BB * NHH * TT * 4;
    float* cm = (float*)ws;

    hipMemsetAsync(a, 0, (size_t)(BB * NHH * TT + BB * HH) * 4, stream);  // a + cm

    cvt_bf16<<<2048, 256, 0, stream>>>(x, xb, MM * HH / 4);
    cvt_w3  <<<dim3(512, 3), 256, 0, stream>>>(Wq, Wk, Wv, Wb);

    proj_mfma <<<dim3(64, 24),      256, 0, stream>>>(xb, Wb, qp, kp, vp);
    attn_fused<<<dim3(16, NHH, BB), 256, 0, stream>>>(qp, kp, a);
    ctx_mean  <<<dim3(NHH, BB, 8),  256, 0, stream>>>(vp, a, cm);
    out_proj  <<<dim3(16, BB),      256, 0, stream>>>(cm, Wo, bo, out);
}